// Round 2
// baseline (859.034 us; speedup 1.0000x reference)
//
#include <hip/hip_runtime.h>
#include <math.h>

#define NLAYER 3
#define LREADx 512
#define NSEQx  96

__device__ __forceinline__ float fsigmoid(float v){ return 1.f/(1.f+__expf(-v)); }
__device__ __forceinline__ float fsoftplus(float v){ return fmaxf(v,0.f) + __logf(1.f + __expf(-fabsf(v))); }

template<int CTRL>
__device__ __forceinline__ float dpp_add(float v){
  int x = __builtin_amdgcn_update_dpp(0, __float_as_int(v), CTRL, 0xF, 0xF, true);
  return v + __int_as_float(x);
}

// ---------------- expander: h = reads @ ew.T + eb ----------------
__global__ __launch_bounds__(256) void k_exp(const float* __restrict__ reads,
    const float* __restrict__ ew, const float* __restrict__ eb, float* __restrict__ h){
  int idx = blockIdx.x*256 + threadIdx.x;     // NROWS*64
  int d = idx & 63;
  int row = idx >> 6;
  float4 r4 = *(const float4*)(reads + (size_t)row*4);
  float4 w4 = *(const float4*)(ew + d*4);
  h[idx] = fmaf(r4.x,w4.x, fmaf(r4.y,w4.y, fmaf(r4.z,w4.z, fmaf(r4.w,w4.w, eb[d]))));
}

// ---------------- fused in_proj + causal conv(k=4) + silu + z-gate precompute ----------------
// block = 32 rows (same b), 256 threads. j<128 -> x path (pre-act staged in LDS, conv applied
// in-block); j>=128 -> z path (written as silu(z) directly).
__global__ __launch_bounds__(256) void k_xzc(const float* __restrict__ h,
    const float* __restrict__ w, const float* __restrict__ cw, const float* __restrict__ cb,
    float* __restrict__ x, float* __restrict__ zsil){
  __shared__ float xp[35][128];
  int j = threadIdx.x;
  int row0 = blockIdx.x*32;
  int l0 = row0 & 511;
  bool isx = j < 128;
  float4 wr[16];
  #pragma unroll
  for (int k=0;k<16;k++) wr[k] = *(const float4*)(w + j*64 + k*4);
  // warm-up rows (pre-activation only), x threads
  if (isx){
    #pragma unroll
    for (int r=0;r<3;r++){
      float a = 0.f;
      if (l0 != 0){
        const float4* hr = (const float4*)(h + (size_t)(row0-3+r)*64);
        #pragma unroll
        for (int k=0;k<16;k++){
          float4 hv = hr[k];
          a = fmaf(hv.x,wr[k].x, fmaf(hv.y,wr[k].y, fmaf(hv.z,wr[k].z, fmaf(hv.w,wr[k].w, a))));
        }
      }
      xp[r][j] = a;
    }
  }
  for (int r=0;r<32;r++){
    const float4* hr = (const float4*)(h + (size_t)(row0+r)*64);
    float a = 0.f;
    #pragma unroll
    for (int k=0;k<16;k++){
      float4 hv = hr[k];
      a = fmaf(hv.x,wr[k].x, fmaf(hv.y,wr[k].y, fmaf(hv.z,wr[k].z, fmaf(hv.w,wr[k].w, a))));
    }
    if (isx) xp[3+r][j] = a;
    else     zsil[(size_t)(row0+r)*128 + (j-128)] = a * fsigmoid(a);
  }
  __syncthreads();
  // conv phase: all 256 threads, each 16 rows of one column
  int c = j & 127, half = j >> 7;
  float4 w4 = *(const float4*)(cw + c*4);
  float bv = cb[c];
  #pragma unroll
  for (int r=half*16; r<half*16+16; r++){
    float a = fmaf(xp[r][c],w4.x, fmaf(xp[r+1][c],w4.y, fmaf(xp[r+2][c],w4.z,
              fmaf(xp[r+3][c],w4.w, bv))));
    x[(size_t)(row0+r)*128 + c] = a * fsigmoid(a);
  }
}

// ---------------- x_proj (K=128,N=36) + dt=softplus(..) + B/C interleave ----------------
__global__ __launch_bounds__(256) void k_xd(const float* __restrict__ x,
    const float* __restrict__ xwT, const float* __restrict__ dtw,
    const float* __restrict__ dtb, float* __restrict__ dt, float* __restrict__ bc){
  __shared__ float4 xd03[256];
  __shared__ float  bcs[256][33];
  int t = threadIdx.x;
  int row = blockIdx.x*256 + t;
  float acc[36];
  #pragma unroll
  for (int c=0;c<36;c++) acc[c]=0.f;
  const float4* xr = (const float4*)(x + (size_t)row*128);
  for (int k4=0;k4<32;k4++){
    float4 xv = xr[k4];
    float xa[4] = {xv.x, xv.y, xv.z, xv.w};
    #pragma unroll
    for (int kk=0;kk<4;kk++){
      const float* wk = xwT + (k4*4+kk)*36;   // uniform -> SMEM
      #pragma unroll
      for (int c=0;c<36;c++) acc[c] = fmaf(xa[kk], wk[c], acc[c]);
    }
  }
  xd03[t] = make_float4(acc[0],acc[1],acc[2],acc[3]);
  #pragma unroll
  for (int nn=0;nn<16;nn++){ bcs[t][2*nn] = acc[4+nn]; bcs[t][2*nn+1] = acc[20+nn]; }
  __syncthreads();
  int d = t & 127, half = t >> 7;
  float4 w4 = *(const float4*)(dtw + d*4);
  float bv = dtb[d];
  size_t row0 = (size_t)blockIdx.x*256;
  for (int rr=half; rr<256; rr+=2){
    float4 s4 = xd03[rr];
    float v = fmaf(s4.x,w4.x, fmaf(s4.y,w4.y, fmaf(s4.z,w4.z, fmaf(s4.w,w4.w, bv))));
    dt[(row0+rr)*128 + d] = fsoftplus(v);
  }
  for (int i=t; i<256*32; i+=256){
    int r = i >> 5, cc = i & 31;
    bc[(row0+r)*32 + cc] = bcs[r][cc];
  }
}

// ---------------- selective scan ----------------
__global__ __launch_bounds__(256) void k_scan(const float* __restrict__ dt,
    const float* __restrict__ x, const float* __restrict__ zsil,
    const float* __restrict__ bc, const float* __restrict__ alog,
    const float* __restrict__ Dp, float* __restrict__ y){
  __shared__ float2 dd[64*16];
  __shared__ float2 bcs[64*16];
  __shared__ float  xs[64*16];
  __shared__ float  zss[64*16];
  __shared__ float  ys[64*16];
  int t = threadIdx.x;
  int b  = blockIdx.x >> 3;
  int dg = blockIdx.x & 7;
  int dl = t >> 4, n = t & 15;
  float aL = -__expf(alog[(dg*16+dl)*16 + n]) * 1.44269504f;   // A * log2(e)
  float Dv = Dp[dg*16 + (t & 15)];
  float hs = 0.f;
  int lt = t >> 2, q = t & 3;
  size_t rowbase = ((size_t)b*LREADx)*128 + dg*16;
  size_t bcbase  = ((size_t)b*LREADx)*32;
  for (int c=0;c<8;c++){
    int l0 = c*64;
    { // stage 64 timesteps
      size_t g = rowbase + (size_t)(l0+lt)*128 + q*4;
      float4 d4 = *(const float4*)(dt + g);
      float4 x4 = *(const float4*)(x + g);
      float4 z4 = *(const float4*)(zsil + g);
      int e = lt*16 + q*4;
      dd[e+0] = make_float2(d4.x, d4.x*x4.x);
      dd[e+1] = make_float2(d4.y, d4.y*x4.y);
      dd[e+2] = make_float2(d4.z, d4.z*x4.z);
      dd[e+3] = make_float2(d4.w, d4.w*x4.w);
      *(float4*)(xs+e)  = x4;
      *(float4*)(zss+e) = z4;
      size_t gb = bcbase + (size_t)(l0+lt)*32 + q*4;
      float4 b0 = *(const float4*)(bc + gb);
      float4 b1 = *(const float4*)(bc + gb + 16);
      *(float4*)((float*)bcs + lt*32 + q*4)      = b0;
      *(float4*)((float*)bcs + lt*32 + 16 + q*4) = b1;
    }
    __syncthreads();
    #pragma unroll 16
    for (int l=0;l<64;l++){
      float2 dv = dd[l*16 + dl];
      float2 bv = bcs[l*16 + n];
      float e = __builtin_amdgcn_exp2f(dv.x * aL);
      hs = fmaf(e, hs, dv.y * bv.x);
      float p = hs * bv.y;
      p = dpp_add<0x121>(p);   // row_ror:1
      p = dpp_add<0x122>(p);   // row_ror:2
      p = dpp_add<0x124>(p);   // row_ror:4
      p = dpp_add<0x128>(p);   // row_ror:8
      if (n == 0) ys[l*16 + dl] = p;
    }
    __syncthreads();
    #pragma unroll
    for (int i=0;i<4;i++){
      int idx = t + i*256;
      float v = (ys[idx] + xs[idx]*Dv) * zss[idx];
      int le = idx >> 4, de = idx & 15;
      y[rowbase + (size_t)(l0+le)*128 + de] = v;
    }
    __syncthreads();
  }
}

// ---------------- out proj + LayerNorm + ReLU ----------------
// 256 threads = 4 waves; ow staged in LDS (XOR-swizzled float4, conflict-free b128 reads);
// each wave handles 8 rows (row uniform within wave), LN via 64-lane shuffles.
__global__ __launch_bounds__(256) void k_out(const float* __restrict__ y,
    const float* __restrict__ ow, const float* __restrict__ lnw,
    const float* __restrict__ lnb, float* __restrict__ h){
  __shared__ float4 wl[2048];   // 64 cols x 32 k4, swizzled
  int t = threadIdx.x;
  for (int i=t; i<2048; i+=256){
    int jj = i >> 5, kk = i & 31;
    wl[jj*32 + (kk ^ (jj & 7))] = *(const float4*)(ow + jj*128 + kk*4);
  }
  __syncthreads();
  int j = t & 63, wv = t >> 6;
  int row0 = blockIdx.x*32 + wv*8;
  float lw = lnw[j], lb = lnb[j];
  for (int r=0;r<8;r++){
    const float4* yr = (const float4*)(y + (size_t)(row0+r)*128);
    float a = 0.f;
    #pragma unroll
    for (int k4=0;k4<32;k4++){
      float4 w4 = wl[j*32 + (k4 ^ (j & 7))];
      float4 yv = yr[k4];   // uniform within wave -> scalar path
      a = fmaf(yv.x,w4.x, fmaf(yv.y,w4.y, fmaf(yv.z,w4.z, fmaf(yv.w,w4.w, a))));
    }
    float s = a;
    #pragma unroll
    for (int off=1;off<64;off<<=1) s += __shfl_xor(s, off, 64);
    float m = s * (1.f/64.f);
    float dv = a - m;
    float s2 = dv*dv;
    #pragma unroll
    for (int off=1;off<64;off<<=1) s2 += __shfl_xor(s2, off, 64);
    float o = dv * rsqrtf(s2*(1.f/64.f) + 1e-5f) * lw + lb;
    h[(size_t)(row0+r)*64 + j] = fmaxf(o, 0.f);
  }
}

// ---------------- mean + last pooling -> enc ----------------
__global__ __launch_bounds__(512) void k_pool(const float* __restrict__ h, float* __restrict__ enc){
  __shared__ float ps[8][64];
  int t = threadIdx.x;
  int w = t >> 6, d = t & 63;
  int b = blockIdx.x;
  const float* hb = h + (size_t)b*LREADx*64;
  float s = 0.f;
  #pragma unroll 8
  for (int i=0;i<64;i++) s += hb[(size_t)(w*64+i)*64 + d];
  ps[w][d] = s;
  __syncthreads();
  if (w == 0){
    float acc = 0.f;
    #pragma unroll
    for (int i=0;i<8;i++) acc += ps[i][d];
    enc[b*128 + d]      = acc * (1.f/512.f);
    enc[b*128 + 64 + d] = hb[(size_t)511*64 + d];
  }
}

// ---------------- q,k projections ----------------
__global__ __launch_bounds__(256) void k_qk(const float* __restrict__ enc,
    const int* __restrict__ sidx, const float* __restrict__ qw, const float* __restrict__ qb,
    const float* __restrict__ kw, const float* __restrict__ kb,
    float* __restrict__ qbuf, float* __restrict__ kbuf){
  int idx = blockIdx.x*256 + threadIdx.x;
  if (idx < NSEQx*64){
    int qi = idx >> 6, j = idx & 63;
    const float* er = enc + (size_t)sidx[qi]*128;
    const float* wr = qw + j*128;
    float a = qb[j];
    for (int k=0;k<32;k++){
      float4 e4 = *(const float4*)(er + k*4);
      float4 w4 = *(const float4*)(wr + k*4);
      a = fmaf(e4.x,w4.x, fmaf(e4.y,w4.y, fmaf(e4.z,w4.z, fmaf(e4.w,w4.w, a))));
    }
    qbuf[idx] = a;
  } else {
    int i2 = idx - NSEQx*64;
    int ki = i2 >> 6, j = i2 & 63;
    const float* er = enc + (size_t)ki*128;
    const float* wr = kw + j*128;
    float a = kb[j];
    for (int k=0;k<32;k++){
      float4 e4 = *(const float4*)(er + k*4);
      float4 w4 = *(const float4*)(wr + k*4);
      a = fmaf(e4.x,w4.x, fmaf(e4.y,w4.y, fmaf(e4.z,w4.z, fmaf(e4.w,w4.w, a))));
    }
    kbuf[i2] = a;
  }
}

// ---------------- scores ----------------
__global__ __launch_bounds__(256) void k_score(const float* __restrict__ qbuf,
    const float* __restrict__ kbuf, const float* __restrict__ mixw,
    const float* __restrict__ mixb, float* __restrict__ out){
  int idx = blockIdx.x*256 + threadIdx.x;
  int ki = idx & 127, qi = idx >> 7;
  const float* qr = qbuf + qi*64;
  const float* kr = kbuf + ki*64;
  float s[4];
  #pragma unroll
  for (int hh=0;hh<4;hh++){
    float a = 0.f;
    #pragma unroll
    for (int k=0;k<4;k++){
      float4 q4 = *(const float4*)(qr + hh*16 + k*4);
      float4 k4 = *(const float4*)(kr + hh*16 + k*4);
      a = fmaf(q4.x,k4.x, fmaf(q4.y,k4.y, fmaf(q4.z,k4.z, fmaf(q4.w,k4.w, a))));
    }
    s[hh] = fmaxf(a, 0.f);
  }
  float best = -1e30f;
  #pragma unroll
  for (int hh=0;hh<4;hh++){
    float v = mixb[hh];
    #pragma unroll
    for (int h2=0;h2<4;h2++) v = fmaf(s[h2], mixw[hh*4+h2], v);
    best = fmaxf(best, v);
  }
  out[idx] = best;
}

// ---------------- transpose x_proj_w once ----------------
__global__ __launch_bounds__(256) void k_trans(const float* __restrict__ xw, float* __restrict__ xwT){
  int i = threadIdx.x + blockIdx.x*256;
  if (i < NLAYER*36*128){
    int l = i / 4608, rem = i % 4608;
    int c = rem >> 7, k = rem & 127;
    xwT[l*4608 + k*36 + c] = xw[i];
  }
}

extern "C" void kernel_launch(void* const* d_in, const int* in_sizes, int n_in,
                              void* d_out, int out_size, void* d_ws, size_t ws_size,
                              hipStream_t stream) {
  (void)in_sizes; (void)n_in; (void)out_size; (void)ws_size;
  const float* reads = (const float*)d_in[0];
  const int*   sidx  = (const int*)d_in[1];
  const float* ew    = (const float*)d_in[2];
  const float* eb    = (const float*)d_in[3];
  const float* inw   = (const float*)d_in[4];
  const float* cw    = (const float*)d_in[5];
  const float* cb    = (const float*)d_in[6];
  const float* xw    = (const float*)d_in[7];
  const float* dtw   = (const float*)d_in[8];
  const float* dtb   = (const float*)d_in[9];
  const float* alog  = (const float*)d_in[10];
  const float* Dp    = (const float*)d_in[11];
  const float* ow    = (const float*)d_in[12];
  const float* lnw   = (const float*)d_in[13];
  const float* lnb   = (const float*)d_in[14];
  const float* qw    = (const float*)d_in[15];
  const float* qb    = (const float*)d_in[16];
  const float* kw    = (const float*)d_in[17];
  const float* kb    = (const float*)d_in[18];
  const float* mixw  = (const float*)d_in[19];
  const float* mixb  = (const float*)d_in[20];

  float* ws  = (float*)d_ws;
  float* h   = ws;                 // 4,194,304
  float* yx  = ws + 4194304;       // 8,388,608 (y)
  float* zs  = ws + 12582912;      // 8,388,608
  float* x   = ws + 20971520;      // 8,388,608
  float* dt  = ws + 29360128;      // 8,388,608
  float* bc  = ws + 37748736;      // 2,097,152
  float* enc = ws + 39845888;      // 16,384
  float* qk  = ws + 39862272;      // 6144 + 8192
  float* xwT = ws + 39876608;      // 13,824

  k_trans<<<54, 256, 0, stream>>>(xw, xwT);
  k_exp<<<16384, 256, 0, stream>>>(reads, ew, eb, h);
  for (int l = 0; l < NLAYER; l++){
    k_xzc <<<2048, 256, 0, stream>>>(h, inw + l*16384, cw + l*512, cb + l*128, x, zs);
    k_xd  <<<256, 256, 0, stream>>>(x, xwT + l*4608, dtw + l*512, dtb + l*128, dt, bc);
    k_scan<<<1024, 256, 0, stream>>>(dt, x, zs, bc, alog + l*2048, Dp + l*128, yx);
    k_out <<<2048, 256, 0, stream>>>(yx, ow + l*8192, lnw + l*64, lnb + l*64, h);
  }
  k_pool <<<128, 512, 0, stream>>>(h, enc);
  k_qk   <<<56, 256, 0, stream>>>(enc, sidx, qw, qb, kw, kb, qk, qk + 6144);
  k_score<<<48, 256, 0, stream>>>(qk, qk + 6144, mixw, mixb, (float*)d_out);
}